// Round 3
// baseline (1545.267 us; speedup 1.0000x reference)
//
#include <hip/hip_runtime.h>
#include <hip/hip_bf16.h>

#define N 1024
#define D 128

typedef __hip_bfloat16 bf16;
typedef __attribute__((ext_vector_type(8))) short bfx8;    // 8 bf16 (4 VGPRs) MFMA A/B frag
typedef __attribute__((ext_vector_type(4))) float fx4;     // MFMA C/D frag
typedef __attribute__((ext_vector_type(4))) unsigned short u16x4;

__device__ __forceinline__ float b2f(bf16 x) { return __bfloat162float(x); }
__device__ __forceinline__ short f2bf_bits(float x) {
    bf16 b = __float2bfloat16(x);
    return *reinterpret_cast<short*>(&b);
}

__device__ __forceinline__ float fast_tanh(float x) {
    float e = __expf(2.f * x);
    return 1.f - 2.f / (e + 1.f);
}
__device__ __forceinline__ float fast_sigmoid(float x) {
    return 1.f / (1.f + __expf(-x));
}

// ---------------- K0a: dtype sniff ----------------
__global__ void sniff_kernel(const unsigned short* __restrict__ xu, int* __restrict__ flag) {
    int l = threadIdx.x;  // 64 threads
    int cnt = 0;
#pragma unroll
    for (int k = 0; k < 8; ++k) {
        unsigned short u = xu[2 * (l * 8 + k)];
        int e = (u >> 7) & 0xFF;
        cnt += (e >= 96 && e <= 144) ? 1 : 0;
    }
    for (int off = 32; off > 0; off >>= 1) cnt += __shfl_down(cnt, off);
    if (l == 0) *flag = (cnt > 400) ? 1 : 0;
}

// ---------------- K0b: convert all inputs to fp32 in ws ----------------
struct ConvArgs {
    const void* p[8];
    float* o[8];
    int n[8];
};
__global__ void convert_kernel(ConvArgs A, const int* __restrict__ flag) {
    int seg = blockIdx.y;
    int n = A.n[seg];
    int isbf = *flag;
    const void* p = A.p[seg];
    float* o = A.o[seg];
    for (int i = blockIdx.x * blockDim.x + threadIdx.x; i < n; i += gridDim.x * blockDim.x) {
        float v = isbf ? b2f(((const bf16*)p)[i]) : ((const float*)p)[i];
        o[i] = v;
    }
}

// ---------------- K1: q = X@Wq^T, kT = (X@Wk^T)^T ----------------
__global__ void qk_kernel(const float* __restrict__ X, const float* __restrict__ Wq,
                          const float* __restrict__ Wk,
                          float* __restrict__ q, float* __restrict__ kT) {
    int i = blockIdx.x & (N - 1);
    bool is_k = blockIdx.x >= N;
    int d = threadIdx.x;  // 0..127
    const float* W = is_k ? Wk : Wq;
    float acc = 0.f;
#pragma unroll 8
    for (int c = 0; c < D; ++c)
        acc += X[i * D + c] * W[d * D + c];
    if (is_k) kT[d * N + i] = acc;
    else      q[i * D + d] = acc;
}

// ---------------- K2: scores[i,j] = v . tanh(q_i + k_j), j >= i ----------------
__global__ void scores_kernel(const float* __restrict__ q, const float* __restrict__ kT,
                              const float* __restrict__ v, float* __restrict__ sc) {
    int i = blockIdx.x;
    __shared__ float qs[D];
    __shared__ float vs[D];
    for (int d = threadIdx.x; d < D; d += blockDim.x) {
        qs[d] = q[i * D + d];
        vs[d] = v[d];
    }
    __syncthreads();
    for (int j = i + (int)threadIdx.x; j < N; j += (int)blockDim.x) {
        float s = 0.f;
#pragma unroll 8
        for (int d = 0; d < D; ++d) {
            float x = qs[d] + kT[d * N + j];
            s += vs[d] * fast_tanh(x);
        }
        sc[i * N + j] = s;
    }
}

// ---------------- K3: row softmax over j>=i; zero-fill j<i ----------------
__global__ void softmax_kernel(float* __restrict__ sc) {
    int i = blockIdx.x;
    int tid = threadIdx.x;  // 256 threads
    __shared__ float red[256];
    float sj[4];
    int cnt = 0;
    float m = -1e30f;
    for (int j = i + tid; j < N; j += 256) {
        sj[cnt] = sc[i * N + j];
        m = fmaxf(m, sj[cnt]);
        ++cnt;
    }
    red[tid] = m;
    __syncthreads();
    for (int s = 128; s > 0; s >>= 1) {
        if (tid < s) red[tid] = fmaxf(red[tid], red[tid + s]);
        __syncthreads();
    }
    m = red[0];
    __syncthreads();
    float p[4];
    float l = 0.f;
    for (int it = 0; it < cnt; ++it) {
        p[it] = __expf(sj[it] - m);
        l += p[it];
    }
    red[tid] = l;
    __syncthreads();
    for (int s = 128; s > 0; s >>= 1) {
        if (tid < s) red[tid] += red[tid + s];
        __syncthreads();
    }
    float inv = 1.f / red[0];
    for (int j = tid; j < i; j += 256) sc[i * N + j] = 0.f;
    int it2 = 0;
    for (int j = i + tid; j < N; j += 256, ++it2) sc[i * N + j] = p[it2] * inv;
}

// ---------------- K4: att = w @ X ----------------
__global__ void att_kernel(const float* __restrict__ w, const float* __restrict__ X,
                           float* __restrict__ att) {
    int i = blockIdx.x;
    int d = threadIdx.x;  // 128
    float acc = 0.f;
#pragma unroll 4
    for (int j = 0; j < N; ++j)
        acc += w[i * N + j] * X[j * D + d];
    att[i * D + d] = acc;
}

// ---------------- K5: gi = [X, att] @ w_ih^T + b_ih ----------------
__global__ void gi_kernel(const float* __restrict__ X, const float* __restrict__ att,
                          const float* __restrict__ w_ih, const float* __restrict__ b_ih,
                          float* __restrict__ gi) {
    int i = blockIdx.x;
    int o = threadIdx.x;  // 0..383
    float acc = b_ih[o];
    const float* wr = w_ih + o * (2 * D);
#pragma unroll 8
    for (int c = 0; c < D; ++c) acc += X[i * D + c] * wr[c];
#pragma unroll 8
    for (int c = 0; c < D; ++c) acc += att[i * D + c] * wr[D + c];
    gi[i * 3 * D + o] = acc;
}

// ---------------- K6: sequential GRU via MFMA matvec ----------------
// 512 threads = 8 waves, 2/SIMD. Wave w owns outputs d in [16w, 16w+16) through
// m-tiles {w, w+8, w+16} (= r/z/n gate rows for those d). Weights stay in regs
// as bf16 A-frags (A[m=lane&15][k=(lane>>4)*8+j]); h round-trips through LDS as
// 128 bf16, read as broadcast B-frags (all 16 cols = same h, so every lane's
// D-frag holds rows (lane>>4)*4+r — gates computed in-register, no gh LDS trip).
// h carried in fp32 registers; double-buffered h_bf -> ONE barrier per step.
__global__ void __launch_bounds__(512) gru_kernel(const float* __restrict__ gi,
                                                  const float* __restrict__ w_hh,
                                                  const float* __restrict__ b_hh,
                                                  void* __restrict__ out,
                                                  const int* __restrict__ flag) {
    __shared__ short h_bf[2][D];
    int t = threadIdx.x;
    int w = t >> 6;
    int l = t & 63;
    int q = l >> 4;       // quad index: selects k-chunk-of-8 in A/B, row-quad in D
    int nn = l & 15;      // A row-in-tile / B column (replicated)
    int dbase = 16 * w + 4 * q;   // this lane's 4 output rows d = dbase + r
    int isbf = *flag;

    // --- preload A-fragments (weights, bf16) ---
    bfx8 a[3][4];
#pragma unroll
    for (int tau = 0; tau < 3; ++tau) {
#pragma unroll
        for (int kc = 0; kc < 4; ++kc) {
            int row = 16 * w + 128 * tau + nn;
            int k0 = 32 * kc + 8 * q;
#pragma unroll
            for (int j = 0; j < 8; ++j)
                a[tau][kc][j] = f2bf_bits(w_hh[row * D + k0 + j]);
        }
    }
    // --- biases for this lane's 4 d's ---
    float bh[3][4];
#pragma unroll
    for (int tau = 0; tau < 3; ++tau)
#pragma unroll
        for (int r = 0; r < 4; ++r)
            bh[tau][r] = b_hh[128 * tau + dbase + r];

    float h[4] = {0.f, 0.f, 0.f, 0.f};
    if (t < D) h_bf[0][t] = 0;
    __syncthreads();

    for (int step = 0; step < N; ++step) {
        int rb = step & 1;          // read buffer
        // prefetch gi for this lane's d's (independent of h)
        const float* g = gi + step * 3 * D + dbase;
        fx4 gr4 = *(const fx4*)(g);
        fx4 gz4 = *(const fx4*)(g + D);
        fx4 gn4 = *(const fx4*)(g + 2 * D);

        // B-frags: h as bf16, lane holds h[32kc + 8q .. +7]
        bfx8 b[4];
#pragma unroll
        for (int kc = 0; kc < 4; ++kc)
            b[kc] = *(const bfx8*)&h_bf[rb][32 * kc + 8 * q];

        fx4 acc0 = {0.f, 0.f, 0.f, 0.f};
        fx4 acc1 = {0.f, 0.f, 0.f, 0.f};
        fx4 acc2 = {0.f, 0.f, 0.f, 0.f};
#pragma unroll
        for (int kc = 0; kc < 4; ++kc) {
            acc0 = __builtin_amdgcn_mfma_f32_16x16x32_bf16(a[0][kc], b[kc], acc0, 0, 0, 0);
            acc1 = __builtin_amdgcn_mfma_f32_16x16x32_bf16(a[1][kc], b[kc], acc1, 0, 0, 0);
            acc2 = __builtin_amdgcn_mfma_f32_16x16x32_bf16(a[2][kc], b[kc], acc2, 0, 0, 0);
        }

        // gates, in-register (replicated across the 16 nn-copies)
        u16x4 hp;
#pragma unroll
        for (int r = 0; r < 4; ++r) {
            float rr = fast_sigmoid(gr4[r] + acc0[r] + bh[0][r]);
            float zz = fast_sigmoid(gz4[r] + acc1[r] + bh[1][r]);
            float nst = fast_tanh(gn4[r] + rr * (acc2[r] + bh[2][r]));
            h[r] = (1.f - zz) * nst + zz * h[r];
            hp[r] = (unsigned short)f2bf_bits(h[r]);
        }
        if (nn == 0) {
            *(u16x4*)&h_bf[rb ^ 1][dbase] = hp;   // next step's B input
            if (isbf) {
                *(u16x4*)((unsigned short*)out + step * D + dbase) = hp;
            } else {
                fx4 hf = {h[0], h[1], h[2], h[3]};
                *(fx4*)((float*)out + step * D + dbase) = hf;
            }
        }
        __syncthreads();
    }
}

extern "C" void kernel_launch(void* const* d_in, const int* in_sizes, int n_in,
                              void* d_out, int out_size, void* d_ws, size_t ws_size,
                              hipStream_t stream) {
    (void)in_sizes; (void)n_in; (void)out_size; (void)ws_size;

    float* w0 = (float*)d_ws;
    int*   flag = (int*)w0;
    float* Xf   = w0 + 16;
    float* Wqf  = Xf   + N * D;
    float* Wkf  = Wqf  + D * D;
    float* vf   = Wkf  + D * D;
    float* wihf = vf   + D;
    float* whhf = wihf + 3 * D * 2 * D;
    float* bihf = whhf + 3 * D * D;
    float* bhhf = bihf + 3 * D;
    float* q    = bhhf + 3 * D;
    float* kT   = q    + N * D;
    float* sc   = kT   + N * D;
    float* att  = sc   + (size_t)N * N;
    float* gi   = att  + N * D;

    sniff_kernel<<<1, 64, 0, stream>>>((const unsigned short*)d_in[0], flag);

    ConvArgs A;
    A.p[0] = d_in[0]; A.o[0] = Xf;   A.n[0] = N * D;
    A.p[1] = d_in[1]; A.o[1] = Wqf;  A.n[1] = D * D;
    A.p[2] = d_in[2]; A.o[2] = Wkf;  A.n[2] = D * D;
    A.p[3] = d_in[3]; A.o[3] = vf;   A.n[3] = D;
    A.p[4] = d_in[4]; A.o[4] = wihf; A.n[4] = 3 * D * 2 * D;
    A.p[5] = d_in[5]; A.o[5] = whhf; A.n[5] = 3 * D * D;
    A.p[6] = d_in[6]; A.o[6] = bihf; A.n[6] = 3 * D;
    A.p[7] = d_in[7]; A.o[7] = bhhf; A.n[7] = 3 * D;
    dim3 cgrid(128, 8, 1);
    convert_kernel<<<cgrid, 256, 0, stream>>>(A, flag);

    qk_kernel<<<2 * N, D, 0, stream>>>(Xf, Wqf, Wkf, q, kT);
    scores_kernel<<<N, 256, 0, stream>>>(q, kT, vf, sc);
    softmax_kernel<<<N, 256, 0, stream>>>(sc);
    att_kernel<<<N, D, 0, stream>>>(sc, Xf, att);
    gi_kernel<<<N, 3 * D, 0, stream>>>(Xf, att, wihf, bihf, gi);
    gru_kernel<<<1, 512, 0, stream>>>(gi, whhf, bhhf, d_out, flag);
}

// Round 4
// 1241.676 us; speedup vs baseline: 1.2445x; 1.2445x over previous
//
#include <hip/hip_runtime.h>
#include <hip/hip_bf16.h>

#define N 1024
#define D 128
#define SB 32          // steps per superstep (gi chunk staged in LDS)
#define NSB (N / SB)

typedef __hip_bfloat16 bf16;
typedef __attribute__((ext_vector_type(8))) short bfx8;    // 8 bf16 (4 VGPRs) MFMA A/B frag
typedef __attribute__((ext_vector_type(4))) float fx4;     // MFMA C/D frag
typedef __attribute__((ext_vector_type(4))) unsigned short u16x4;
typedef __attribute__((ext_vector_type(8))) unsigned short u16x8;

__device__ __forceinline__ float b2f(bf16 x) { return __bfloat162float(x); }
__device__ __forceinline__ short f2bf_bits(float x) {
    bf16 b = __float2bfloat16(x);
    return *reinterpret_cast<short*>(&b);
}
__device__ __forceinline__ float bfbits2f(unsigned short u) {
    return __uint_as_float(((unsigned int)u) << 16);
}

__device__ __forceinline__ float fast_tanh(float x) {
    float e = __expf(2.f * x);
    return 1.f - 2.f / (e + 1.f);
}
__device__ __forceinline__ float fast_sigmoid(float x) {
    return 1.f / (1.f + __expf(-x));
}

// ---------------- K0a: dtype sniff ----------------
__global__ void sniff_kernel(const unsigned short* __restrict__ xu, int* __restrict__ flag) {
    int l = threadIdx.x;  // 64 threads
    int cnt = 0;
#pragma unroll
    for (int k = 0; k < 8; ++k) {
        unsigned short u = xu[2 * (l * 8 + k)];
        int e = (u >> 7) & 0xFF;
        cnt += (e >= 96 && e <= 144) ? 1 : 0;
    }
    for (int off = 32; off > 0; off >>= 1) cnt += __shfl_down(cnt, off);
    if (l == 0) *flag = (cnt > 400) ? 1 : 0;
}

// ---------------- K0b: convert all inputs to fp32 in ws ----------------
struct ConvArgs {
    const void* p[8];
    float* o[8];
    int n[8];
};
__global__ void convert_kernel(ConvArgs A, const int* __restrict__ flag) {
    int seg = blockIdx.y;
    int n = A.n[seg];
    int isbf = *flag;
    const void* p = A.p[seg];
    float* o = A.o[seg];
    for (int i = blockIdx.x * blockDim.x + threadIdx.x; i < n; i += gridDim.x * blockDim.x) {
        float v = isbf ? b2f(((const bf16*)p)[i]) : ((const float*)p)[i];
        o[i] = v;
    }
}

// ---------------- K1: q = X@Wq^T, kT = (X@Wk^T)^T ----------------
__global__ void qk_kernel(const float* __restrict__ X, const float* __restrict__ Wq,
                          const float* __restrict__ Wk,
                          float* __restrict__ q, float* __restrict__ kT) {
    int i = blockIdx.x & (N - 1);
    bool is_k = blockIdx.x >= N;
    int d = threadIdx.x;  // 0..127
    const float* W = is_k ? Wk : Wq;
    float acc = 0.f;
#pragma unroll 8
    for (int c = 0; c < D; ++c)
        acc += X[i * D + c] * W[d * D + c];
    if (is_k) kT[d * N + i] = acc;
    else      q[i * D + d] = acc;
}

// ---------------- K2: scores[i,j] = v . tanh(q_i + k_j), j >= i ----------------
__global__ void scores_kernel(const float* __restrict__ q, const float* __restrict__ kT,
                              const float* __restrict__ v, float* __restrict__ sc) {
    int i = blockIdx.x;
    __shared__ float qs[D];
    __shared__ float vs[D];
    for (int d = threadIdx.x; d < D; d += blockDim.x) {
        qs[d] = q[i * D + d];
        vs[d] = v[d];
    }
    __syncthreads();
    for (int j = i + (int)threadIdx.x; j < N; j += (int)blockDim.x) {
        float s = 0.f;
#pragma unroll 8
        for (int d = 0; d < D; ++d) {
            float x = qs[d] + kT[d * N + j];
            s += vs[d] * fast_tanh(x);
        }
        sc[i * N + j] = s;
    }
}

// ---------------- K3: row softmax over j>=i; zero-fill j<i ----------------
__global__ void softmax_kernel(float* __restrict__ sc) {
    int i = blockIdx.x;
    int tid = threadIdx.x;  // 256 threads
    __shared__ float red[256];
    float sj[4];
    int cnt = 0;
    float m = -1e30f;
    for (int j = i + tid; j < N; j += 256) {
        sj[cnt] = sc[i * N + j];
        m = fmaxf(m, sj[cnt]);
        ++cnt;
    }
    red[tid] = m;
    __syncthreads();
    for (int s = 128; s > 0; s >>= 1) {
        if (tid < s) red[tid] = fmaxf(red[tid], red[tid + s]);
        __syncthreads();
    }
    m = red[0];
    __syncthreads();
    float p[4];
    float l = 0.f;
    for (int it = 0; it < cnt; ++it) {
        p[it] = __expf(sj[it] - m);
        l += p[it];
    }
    red[tid] = l;
    __syncthreads();
    for (int s = 128; s > 0; s >>= 1) {
        if (tid < s) red[tid] += red[tid + s];
        __syncthreads();
    }
    float inv = 1.f / red[0];
    for (int j = tid; j < i; j += 256) sc[i * N + j] = 0.f;
    int it2 = 0;
    for (int j = i + tid; j < N; j += 256, ++it2) sc[i * N + j] = p[it2] * inv;
}

// ---------------- K4: att = w @ X ----------------
__global__ void att_kernel(const float* __restrict__ w, const float* __restrict__ X,
                           float* __restrict__ att) {
    int i = blockIdx.x;
    int d = threadIdx.x;  // 128
    float acc = 0.f;
#pragma unroll 4
    for (int j = 0; j < N; ++j)
        acc += w[i * N + j] * X[j * D + d];
    att[i * D + d] = acc;
}

// ---------------- K5: gi = [X, att] @ w_ih^T + b_ih ----------------
__global__ void gi_kernel(const float* __restrict__ X, const float* __restrict__ att,
                          const float* __restrict__ w_ih, const float* __restrict__ b_ih,
                          float* __restrict__ gi) {
    int i = blockIdx.x;
    int o = threadIdx.x;  // 0..383
    float acc = b_ih[o];
    const float* wr = w_ih + o * (2 * D);
#pragma unroll 8
    for (int c = 0; c < D; ++c) acc += X[i * D + c] * wr[c];
#pragma unroll 8
    for (int c = 0; c < D; ++c) acc += att[i * D + c] * wr[D + c];
    gi[i * 3 * D + o] = acc;
}

// ---------------- K6: sequential GRU via MFMA, superstep-staged ----------------
// Structural fix vs R3: the inner per-step loop is 100% vmem-free, so the
// per-step __syncthreads only waits lgkmcnt (no vmcnt(0) HBM drain each step).
// - gi staged into LDS in 32-step chunks (48 KB fp32) once per superstep.
// - hist[33][128] bf16 rolling buffer: step s reads hist[s], writes hist[s+1];
//   doubles as the output staging, flushed 32 rows at a time (coalesced 16B).
// - b_hh folded into MFMA accumulator init.
__global__ void __launch_bounds__(512) gru_kernel(const float* __restrict__ gi,
                                                  const float* __restrict__ w_hh,
                                                  const float* __restrict__ b_hh,
                                                  void* __restrict__ out,
                                                  const int* __restrict__ flag) {
    __shared__ float gi_lds[SB][3 * D];      // 49152 B
    __shared__ short hist[SB + 1][D];        // 8448 B
    int t = threadIdx.x;
    int w = t >> 6;
    int l = t & 63;
    int q = l >> 4;       // quad: k-chunk-of-8 in A/B, row-quad in D
    int nn = l & 15;      // A row-in-tile / B column (replicated)
    int dbase = 16 * w + 4 * q;
    int isbf = *flag;

    // --- preload A-fragments (weights, bf16): A[m=lane&15][k=(lane>>4)*8+j] ---
    bfx8 a[3][4];
#pragma unroll
    for (int tau = 0; tau < 3; ++tau) {
#pragma unroll
        for (int kc = 0; kc < 4; ++kc) {
            int row = 16 * w + 128 * tau + nn;
            int k0 = 32 * kc + 8 * q;
#pragma unroll
            for (int j = 0; j < 8; ++j)
                a[tau][kc][j] = f2bf_bits(w_hh[row * D + k0 + j]);
        }
    }
    // --- biases as accumulator-init fragments (C row = dbase + r) ---
    fx4 bh0, bh1, bh2;
#pragma unroll
    for (int r = 0; r < 4; ++r) {
        bh0[r] = b_hh[dbase + r];
        bh1[r] = b_hh[D + dbase + r];
        bh2[r] = b_hh[2 * D + dbase + r];
    }

    float h[4] = {0.f, 0.f, 0.f, 0.f};
    // flush mapping: lane t handles hist row fr, cols fc..fc+7
    int fr = 1 + (t >> 4);
    int fc = (t & 15) * 8;

    for (int sb = 0; sb < NSB; ++sb) {
        // -- stage gi chunk: 32 steps x 384 floats = 48 KB, 6x16B per lane --
        {
            const fx4* src = (const fx4*)(gi + (size_t)sb * SB * 3 * D);
            fx4* dst = (fx4*)&gi_lds[0][0];
#pragma unroll
            for (int k2 = 0; k2 < 6; ++k2)
                dst[t + k2 * 512] = src[t + k2 * 512];
        }
        // -- flush previous superstep's 32 output rows; carry hist[SB]->hist[0] --
        if (sb == 0) {
            if (t < 64) ((int*)&hist[0][0])[t] = 0;
        } else {
            u16x8 hv = *(const u16x8*)&hist[fr][fc];
            int orow = (sb - 1) * SB + fr - 1;
            if (isbf) {
                *(u16x8*)((unsigned short*)out + orow * D + fc) = hv;
            } else {
                float* op = (float*)out + orow * D + fc;
                fx4 lo, hi;
#pragma unroll
                for (int j = 0; j < 4; ++j) { lo[j] = bfbits2f(hv[j]); hi[j] = bfbits2f(hv[4 + j]); }
                *(fx4*)op = lo;
                *(fx4*)(op + 4) = hi;
            }
            if (t < 64) ((int*)&hist[0][0])[t] = ((const int*)&hist[SB][0])[t];
        }
        __syncthreads();

        // -- vmem-free inner loop --
        for (int s = 0; s < SB; ++s) {
            fx4 g0 = *(const fx4*)&gi_lds[s][dbase];
            fx4 g1 = *(const fx4*)&gi_lds[s][D + dbase];
            fx4 g2 = *(const fx4*)&gi_lds[s][2 * D + dbase];
            bfx8 b[4];
#pragma unroll
            for (int kc = 0; kc < 4; ++kc)
                b[kc] = *(const bfx8*)&hist[s][32 * kc + 8 * q];
            fx4 acc0 = bh0, acc1 = bh1, acc2 = bh2;
#pragma unroll
            for (int kc = 0; kc < 4; ++kc) {
                acc0 = __builtin_amdgcn_mfma_f32_16x16x32_bf16(a[0][kc], b[kc], acc0, 0, 0, 0);
                acc1 = __builtin_amdgcn_mfma_f32_16x16x32_bf16(a[1][kc], b[kc], acc1, 0, 0, 0);
                acc2 = __builtin_amdgcn_mfma_f32_16x16x32_bf16(a[2][kc], b[kc], acc2, 0, 0, 0);
            }
            u16x4 hp;
#pragma unroll
            for (int r = 0; r < 4; ++r) {
                float rr = fast_sigmoid(g0[r] + acc0[r]);
                float zz = fast_sigmoid(g1[r] + acc1[r]);
                float nst = fast_tanh(g2[r] + rr * acc2[r]);
                h[r] = (1.f - zz) * nst + zz * h[r];
                hp[r] = (unsigned short)f2bf_bits(h[r]);
            }
            if (nn == 0) *(u16x4*)&hist[s + 1][dbase] = hp;
            __syncthreads();
        }
    }
    // -- final flush (last superstep's rows) --
    {
        u16x8 hv = *(const u16x8*)&hist[fr][fc];
        int orow = (NSB - 1) * SB + fr - 1;
        if (isbf) {
            *(u16x8*)((unsigned short*)out + orow * D + fc) = hv;
        } else {
            float* op = (float*)out + orow * D + fc;
            fx4 lo, hi;
#pragma unroll
            for (int j = 0; j < 4; ++j) { lo[j] = bfbits2f(hv[j]); hi[j] = bfbits2f(hv[4 + j]); }
            *(fx4*)op = lo;
            *(fx4*)(op + 4) = hi;
        }
    }
}

extern "C" void kernel_launch(void* const* d_in, const int* in_sizes, int n_in,
                              void* d_out, int out_size, void* d_ws, size_t ws_size,
                              hipStream_t stream) {
    (void)in_sizes; (void)n_in; (void)out_size; (void)ws_size;

    float* w0 = (float*)d_ws;
    int*   flag = (int*)w0;
    float* Xf   = w0 + 16;
    float* Wqf  = Xf   + N * D;
    float* Wkf  = Wqf  + D * D;
    float* vf   = Wkf  + D * D;
    float* wihf = vf   + D;
    float* whhf = wihf + 3 * D * 2 * D;
    float* bihf = whhf + 3 * D * D;
    float* bhhf = bihf + 3 * D;
    float* q    = bhhf + 3 * D;
    float* kT   = q    + N * D;
    float* sc   = kT   + N * D;
    float* att  = sc   + (size_t)N * N;
    float* gi   = att  + N * D;

    sniff_kernel<<<1, 64, 0, stream>>>((const unsigned short*)d_in[0], flag);

    ConvArgs A;
    A.p[0] = d_in[0]; A.o[0] = Xf;   A.n[0] = N * D;
    A.p[1] = d_in[1]; A.o[1] = Wqf;  A.n[1] = D * D;
    A.p[2] = d_in[2]; A.o[2] = Wkf;  A.n[2] = D * D;
    A.p[3] = d_in[3]; A.o[3] = vf;   A.n[3] = D;
    A.p[4] = d_in[4]; A.o[4] = wihf; A.n[4] = 3 * D * 2 * D;
    A.p[5] = d_in[5]; A.o[5] = whhf; A.n[5] = 3 * D * D;
    A.p[6] = d_in[6]; A.o[6] = bihf; A.n[6] = 3 * D;
    A.p[7] = d_in[7]; A.o[7] = bhhf; A.n[7] = 3 * D;
    dim3 cgrid(128, 8, 1);
    convert_kernel<<<cgrid, 256, 0, stream>>>(A, flag);

    qk_kernel<<<2 * N, D, 0, stream>>>(Xf, Wqf, Wkf, q, kT);
    scores_kernel<<<N, 256, 0, stream>>>(q, kT, vf, sc);
    softmax_kernel<<<N, 256, 0, stream>>>(sc);
    att_kernel<<<N, D, 0, stream>>>(sc, Xf, att);
    gi_kernel<<<N, 3 * D, 0, stream>>>(Xf, att, wihf, bihf, gi);
    gru_kernel<<<1, 512, 0, stream>>>(gi, whhf, bhhf, d_out, flag);
}

// Round 5
// 689.553 us; speedup vs baseline: 2.2410x; 1.8007x over previous
//
#include <hip/hip_runtime.h>
#include <hip/hip_bf16.h>

#define N 1024
#define D 128
#define SB 32          // steps per superstep (gi chunk staged in LDS)
#define NSB (N / SB)

typedef __hip_bfloat16 bf16;
typedef __attribute__((ext_vector_type(8))) short bfx8;    // 8 bf16 (4 VGPRs) MFMA A/B frag
typedef __attribute__((ext_vector_type(4))) float fx4;     // MFMA C/D frag
typedef __attribute__((ext_vector_type(8))) unsigned short u16x8;

__device__ __forceinline__ float b2f(bf16 x) { return __bfloat162float(x); }
__device__ __forceinline__ short f2bf_bits(float x) {
    bf16 b = __float2bfloat16(x);
    return *reinterpret_cast<short*>(&b);
}
__device__ __forceinline__ float bfbits2f(unsigned short u) {
    return __uint_as_float(((unsigned int)u) << 16);
}
__device__ __forceinline__ float fastrcp(float x) { return __builtin_amdgcn_rcpf(x); }

__device__ __forceinline__ float fast_tanh(float x) {
    // tanh(x) = 1 - 2/(e^{2x}+1); rcp instead of div (no fast-math flag)
    float e = __expf(2.f * x);
    return 1.f - 2.f * fastrcp(e + 1.f);
}
__device__ __forceinline__ float fast_sigmoid(float x) {
    return fastrcp(1.f + __expf(-x));
}

// dynamic extract from fx4 by r (3 cndmask, no branches)
__device__ __forceinline__ float sel4(fx4 v, int r) {
    float x = (r & 1) ? v[1] : v[0];
    float y = (r & 1) ? v[3] : v[2];
    return (r & 2) ? y : x;
}

// async 16B global->LDS (wave-uniform lds base + lane*16; g must be base+lane*16)
__device__ __forceinline__ void async_copy16(const float* g, void* l) {
    __builtin_amdgcn_global_load_lds((const __attribute__((address_space(1))) void*)g,
                                     (__attribute__((address_space(3))) void*)l, 16, 0, 0);
}

// ---------------- K0a: dtype sniff ----------------
__global__ void sniff_kernel(const unsigned short* __restrict__ xu, int* __restrict__ flag) {
    int l = threadIdx.x;  // 64 threads
    int cnt = 0;
#pragma unroll
    for (int k = 0; k < 8; ++k) {
        unsigned short u = xu[2 * (l * 8 + k)];
        int e = (u >> 7) & 0xFF;
        cnt += (e >= 96 && e <= 144) ? 1 : 0;
    }
    for (int off = 32; off > 0; off >>= 1) cnt += __shfl_down(cnt, off);
    if (l == 0) *flag = (cnt > 400) ? 1 : 0;
}

// ---------------- K0b: convert all inputs to fp32 in ws ----------------
struct ConvArgs {
    const void* p[8];
    float* o[8];
    int n[8];
};
__global__ void convert_kernel(ConvArgs A, const int* __restrict__ flag) {
    int seg = blockIdx.y;
    int n = A.n[seg];
    int isbf = *flag;
    const void* p = A.p[seg];
    float* o = A.o[seg];
    for (int i = blockIdx.x * blockDim.x + threadIdx.x; i < n; i += gridDim.x * blockDim.x) {
        float v = isbf ? b2f(((const bf16*)p)[i]) : ((const float*)p)[i];
        o[i] = v;
    }
}

// ---------------- K1: q = X@Wq^T, kT = (X@Wk^T)^T ----------------
__global__ void qk_kernel(const float* __restrict__ X, const float* __restrict__ Wq,
                          const float* __restrict__ Wk,
                          float* __restrict__ q, float* __restrict__ kT) {
    int i = blockIdx.x & (N - 1);
    bool is_k = blockIdx.x >= N;
    int d = threadIdx.x;  // 0..127
    const float* W = is_k ? Wk : Wq;
    float acc = 0.f;
#pragma unroll 8
    for (int c = 0; c < D; ++c)
        acc += X[i * D + c] * W[d * D + c];
    if (is_k) kT[d * N + i] = acc;
    else      q[i * D + d] = acc;
}

// ---------------- K2: scores[i,j] = v . tanh(q_i + k_j), j >= i ----------------
__global__ void scores_kernel(const float* __restrict__ q, const float* __restrict__ kT,
                              const float* __restrict__ v, float* __restrict__ sc) {
    int i = blockIdx.x;
    __shared__ float qs[D];
    __shared__ float vs[D];
    for (int d = threadIdx.x; d < D; d += blockDim.x) {
        qs[d] = q[i * D + d];
        vs[d] = v[d];
    }
    __syncthreads();
    for (int j = i + (int)threadIdx.x; j < N; j += (int)blockDim.x) {
        float s = 0.f;
#pragma unroll 8
        for (int d = 0; d < D; ++d) {
            float x = qs[d] + kT[d * N + j];
            s += vs[d] * fast_tanh(x);
        }
        sc[i * N + j] = s;
    }
}

// ---------------- K3: row softmax over j>=i; zero-fill j<i ----------------
__global__ void softmax_kernel(float* __restrict__ sc) {
    int i = blockIdx.x;
    int tid = threadIdx.x;  // 256 threads
    __shared__ float red[256];
    float sj[4];
    int cnt = 0;
    float m = -1e30f;
    for (int j = i + tid; j < N; j += 256) {
        sj[cnt] = sc[i * N + j];
        m = fmaxf(m, sj[cnt]);
        ++cnt;
    }
    red[tid] = m;
    __syncthreads();
    for (int s = 128; s > 0; s >>= 1) {
        if (tid < s) red[tid] = fmaxf(red[tid], red[tid + s]);
        __syncthreads();
    }
    m = red[0];
    __syncthreads();
    float p[4];
    float l = 0.f;
    for (int it = 0; it < cnt; ++it) {
        p[it] = __expf(sj[it] - m);
        l += p[it];
    }
    red[tid] = l;
    __syncthreads();
    for (int s = 128; s > 0; s >>= 1) {
        if (tid < s) red[tid] += red[tid + s];
        __syncthreads();
    }
    float inv = fastrcp(red[0]);
    for (int j = tid; j < i; j += 256) sc[i * N + j] = 0.f;
    int it2 = 0;
    for (int j = i + tid; j < N; j += 256, ++it2) sc[i * N + j] = p[it2] * inv;
}

// ---------------- K4: att = w @ X ----------------
__global__ void att_kernel(const float* __restrict__ w, const float* __restrict__ X,
                           float* __restrict__ att) {
    int i = blockIdx.x;
    int d = threadIdx.x;  // 128
    float acc = 0.f;
#pragma unroll 4
    for (int j = 0; j < N; ++j)
        acc += w[i * N + j] * X[j * D + d];
    att[i * D + d] = acc;
}

// ---------------- K5: gi = [X, att] @ w_ih^T + b_ih ----------------
__global__ void gi_kernel(const float* __restrict__ X, const float* __restrict__ att,
                          const float* __restrict__ w_ih, const float* __restrict__ b_ih,
                          float* __restrict__ gi) {
    int i = blockIdx.x;
    int o = threadIdx.x;  // 0..383
    float acc = b_ih[o];
    const float* wr = w_ih + o * (2 * D);
#pragma unroll 8
    for (int c = 0; c < D; ++c) acc += X[i * D + c] * wr[c];
#pragma unroll 8
    for (int c = 0; c < D; ++c) acc += att[i * D + c] * wr[D + c];
    gi[i * 3 * D + o] = acc;
}

// ---------------- K6: sequential GRU via MFMA, 4 waves, lane-specialized gates ----
// Wave w owns output rows d in [32w, 32w+32) for all 3 gates: m-tiles mq={2w,2w+1},
// tau={0,1,2}; 24 MFMA/wave/step (16x16x32 bf16), A (weights) resident in VGPRs.
// Gate phase: lane L owns row d = 32w + 16*((L>>3)&1) + 4*(L>>4) + (L&3), selected
// from its OWN acc regs via cndmask (D-layout row=(lane>>4)*4+reg) — no cross-lane.
// gi double-buffered in LDS via async global_load_lds issued one superstep ahead;
// per-step barriers are raw "s_waitcnt lgkmcnt(0); s_barrier" (no vmcnt drain).
__global__ void __launch_bounds__(256, 1) gru_kernel(const float* __restrict__ gi,
                                                     const float* __restrict__ w_hh,
                                                     const float* __restrict__ b_hh,
                                                     void* __restrict__ out,
                                                     const int* __restrict__ flag) {
    __shared__ float gi_lds[2][SB][3 * D];   // 2 x 48 KB
    __shared__ short hist[SB + 1][D];        // 8448 B
    int t = threadIdx.x;
    int w = t >> 6;
    int l = t & 63;
    int q = l >> 4;        // quad: A/B k-subchunk, D row-quad
    int nn = l & 15;       // A m-row / B n-col
    int isbf = *flag;

    // --- A-frags (weights, bf16): a[tau][mqi][kc]; A[m=nn][k=32kc+8q+j] ---
    bfx8 a[3][2][4];
#pragma unroll
    for (int tau = 0; tau < 3; ++tau)
#pragma unroll
        for (int mqi = 0; mqi < 2; ++mqi)
#pragma unroll
            for (int kc = 0; kc < 4; ++kc) {
                int row = 128 * tau + 16 * (2 * w + mqi) + nn;
                int k0 = 32 * kc + 8 * q;
#pragma unroll
                for (int j = 0; j < 8; ++j)
                    a[tau][mqi][kc][j] = f2bf_bits(w_hh[row * D + k0 + j]);
            }

    // --- per-lane gate assignment ---
    int rsel = l & 3;
    int mqsel = (l >> 3) & 1;
    int drow = 32 * w + 16 * mqsel + 4 * q + rsel;   // this lane's output row
    float b_r = b_hh[drow];
    float b_z = b_hh[D + drow];
    float b_n = b_hh[2 * D + drow];
    float h = 0.f;
    bool writer = (l & 4) == 0;   // one writer per distinct drow (2x replication)

    // flush mapping: lane t -> out row fr, 16 cols at fc
    int fr = 1 + (t >> 3);
    int fc = (t & 7) * 16;

    // --- prefetch superstep 0 into buffer 0 ---
    {
        const float* src = gi + (size_t)0;
        for (int m = 0; m < 12; ++m) {
            int off = (w * 12 + m) * 256;   // floats
            async_copy16(src + off + (l << 2), (char*)&gi_lds[0][0][0] + off * 4);
        }
    }

    for (int sb = 0; sb < NSB; ++sb) {
        int cb = sb & 1;
        // -- flush previous superstep's outputs; carry hist[SB]->hist[0] --
        if (sb == 0) {
            if (t < 64) ((int*)&hist[0][0])[t] = 0;
        } else {
            u16x8 h0 = *(const u16x8*)&hist[fr][fc];
            u16x8 h1 = *(const u16x8*)&hist[fr][fc + 8];
            int orow = (sb - 1) * SB + fr - 1;
            if (isbf) {
                *(u16x8*)((unsigned short*)out + orow * D + fc) = h0;
                *(u16x8*)((unsigned short*)out + orow * D + fc + 8) = h1;
            } else {
                float* op = (float*)out + orow * D + fc;
                fx4 f0, f1, f2, f3;
#pragma unroll
                for (int j = 0; j < 4; ++j) {
                    f0[j] = bfbits2f(h0[j]);     f1[j] = bfbits2f(h0[4 + j]);
                    f2[j] = bfbits2f(h1[j]);     f3[j] = bfbits2f(h1[4 + j]);
                }
                *(fx4*)op = f0; *(fx4*)(op + 4) = f1;
                *(fx4*)(op + 8) = f2; *(fx4*)(op + 12) = f3;
            }
            if (t < 64) ((int*)&hist[0][0])[t] = ((const int*)&hist[SB][0])[t];
        }
        // boundary barrier: drain prefetch (issued 32 steps ago) + LDS writes
        asm volatile("s_waitcnt vmcnt(0) lgkmcnt(0)\ns_barrier" ::: "memory");

        // -- issue prefetch for NEXT superstep into the other buffer --
        if (sb + 1 < NSB) {
            const float* src = gi + (size_t)(sb + 1) * SB * 3 * D;
            for (int m = 0; m < 12; ++m) {
                int off = (w * 12 + m) * 256;
                async_copy16(src + off + (l << 2), (char*)&gi_lds[cb ^ 1][0][0] + off * 4);
            }
        }

        // -- vmem-free inner loop (barriers wait lgkmcnt only) --
        for (int s = 0; s < SB; ++s) {
            bfx8 b[4];
#pragma unroll
            for (int kc = 0; kc < 4; ++kc)
                b[kc] = *(const bfx8*)&hist[s][32 * kc + 8 * q];
            float gr = gi_lds[cb][s][drow];
            float gz = gi_lds[cb][s][D + drow];
            float gn = gi_lds[cb][s][2 * D + drow];

            fx4 acc[3][2];
#pragma unroll
            for (int tau = 0; tau < 3; ++tau)
#pragma unroll
                for (int mqi = 0; mqi < 2; ++mqi) {
                    fx4 c = {0.f, 0.f, 0.f, 0.f};
#pragma unroll
                    for (int kc = 0; kc < 4; ++kc)
                        c = __builtin_amdgcn_mfma_f32_16x16x32_bf16(a[tau][mqi][kc], b[kc], c, 0, 0, 0);
                    acc[tau][mqi] = c;
                }

            // lane-specialized gate for row drow
            float ar = mqsel ? sel4(acc[0][1], rsel) : sel4(acc[0][0], rsel);
            float az = mqsel ? sel4(acc[1][1], rsel) : sel4(acc[1][0], rsel);
            float an = mqsel ? sel4(acc[2][1], rsel) : sel4(acc[2][0], rsel);
            float rr = fast_sigmoid(gr + ar + b_r);
            float zz = fast_sigmoid(gz + az + b_z);
            float nst = fast_tanh(gn + rr * (an + b_n));
            h = (1.f - zz) * nst + zz * h;
            if (writer) hist[s + 1][drow] = f2bf_bits(h);
            asm volatile("s_waitcnt lgkmcnt(0)\ns_barrier" ::: "memory");
        }
    }
    // -- final flush --
    {
        u16x8 h0 = *(const u16x8*)&hist[fr][fc];
        u16x8 h1 = *(const u16x8*)&hist[fr][fc + 8];
        int orow = (NSB - 1) * SB + fr - 1;
        if (isbf) {
            *(u16x8*)((unsigned short*)out + orow * D + fc) = h0;
            *(u16x8*)((unsigned short*)out + orow * D + fc + 8) = h1;
        } else {
            float* op = (float*)out + orow * D + fc;
            fx4 f0, f1, f2, f3;
#pragma unroll
            for (int j = 0; j < 4; ++j) {
                f0[j] = bfbits2f(h0[j]);     f1[j] = bfbits2f(h0[4 + j]);
                f2[j] = bfbits2f(h1[j]);     f3[j] = bfbits2f(h1[4 + j]);
            }
            *(fx4*)op = f0; *(fx4*)(op + 4) = f1;
            *(fx4*)(op + 8) = f2; *(fx4*)(op + 12) = f3;
        }
    }
}

extern "C" void kernel_launch(void* const* d_in, const int* in_sizes, int n_in,
                              void* d_out, int out_size, void* d_ws, size_t ws_size,
                              hipStream_t stream) {
    (void)in_sizes; (void)n_in; (void)out_size; (void)ws_size;

    float* w0 = (float*)d_ws;
    int*   flag = (int*)w0;
    float* Xf   = w0 + 16;
    float* Wqf  = Xf   + N * D;
    float* Wkf  = Wqf  + D * D;
    float* vf   = Wkf  + D * D;
    float* wihf = vf   + D;
    float* whhf = wihf + 3 * D * 2 * D;
    float* bihf = whhf + 3 * D * D;
    float* bhhf = bihf + 3 * D;
    float* q    = bhhf + 3 * D;
    float* kT   = q    + N * D;
    float* sc   = kT   + N * D;
    float* att  = sc   + (size_t)N * N;
    float* gi   = att  + N * D;

    sniff_kernel<<<1, 64, 0, stream>>>((const unsigned short*)d_in[0], flag);

    ConvArgs A;
    A.p[0] = d_in[0]; A.o[0] = Xf;   A.n[0] = N * D;
    A.p[1] = d_in[1]; A.o[1] = Wqf;  A.n[1] = D * D;
    A.p[2] = d_in[2]; A.o[2] = Wkf;  A.n[2] = D * D;
    A.p[3] = d_in[3]; A.o[3] = vf;   A.n[3] = D;
    A.p[4] = d_in[4]; A.o[4] = wihf; A.n[4] = 3 * D * 2 * D;
    A.p[5] = d_in[5]; A.o[5] = whhf; A.n[5] = 3 * D * D;
    A.p[6] = d_in[6]; A.o[6] = bihf; A.n[6] = 3 * D;
    A.p[7] = d_in[7]; A.o[7] = bhhf; A.n[7] = 3 * D;
    dim3 cgrid(128, 8, 1);
    convert_kernel<<<cgrid, 256, 0, stream>>>(A, flag);

    qk_kernel<<<2 * N, D, 0, stream>>>(Xf, Wqf, Wkf, q, kT);
    scores_kernel<<<N, 256, 0, stream>>>(q, kT, vf, sc);
    softmax_kernel<<<N, 256, 0, stream>>>(sc);
    att_kernel<<<N, D, 0, stream>>>(sc, Xf, att);
    gi_kernel<<<N, 3 * D, 0, stream>>>(Xf, att, wihf, bihf, gi);
    gru_kernel<<<1, 256, 0, stream>>>(gi, whhf, bhhf, d_out, flag);
}

// Round 6
// 632.838 us; speedup vs baseline: 2.4418x; 1.0896x over previous
//
#include <hip/hip_runtime.h>
#include <hip/hip_bf16.h>

#define N 1024
#define D 128
#define SB 32          // steps per superstep (gi chunk staged in LDS)
#define NSB (N / SB)

typedef __hip_bfloat16 bf16;
typedef __attribute__((ext_vector_type(8))) short bfx8;    // 8 bf16 (4 VGPRs) MFMA A/B frag
typedef __attribute__((ext_vector_type(4))) float fx4;     // MFMA C/D frag
typedef __attribute__((ext_vector_type(8))) unsigned short u16x8;

__device__ __forceinline__ float b2f(bf16 x) { return __bfloat162float(x); }
__device__ __forceinline__ short f2bf_bits(float x) {
    bf16 b = __float2bfloat16(x);
    return *reinterpret_cast<short*>(&b);
}
__device__ __forceinline__ float bfbits2f(unsigned short u) {
    return __uint_as_float(((unsigned int)u) << 16);
}
__device__ __forceinline__ float fastrcp(float x) { return __builtin_amdgcn_rcpf(x); }

__device__ __forceinline__ float fast_tanh(float x) {
    float e = __expf(2.f * x);
    return 1.f - 2.f * fastrcp(e + 1.f);
}
__device__ __forceinline__ float fast_sigmoid(float x) {
    return fastrcp(1.f + __expf(-x));
}

// dynamic extract from fx4 by r (3 cndmask)
__device__ __forceinline__ float sel4(fx4 v, int r) {
    float x = (r & 1) ? v[1] : v[0];
    float y = (r & 1) ? v[3] : v[2];
    return (r & 2) ? y : x;
}

// async 16B global->LDS (lds base wave-uniform; HW scatters lane i at base+i*16)
__device__ __forceinline__ void async_copy16(const float* g, void* l) {
    __builtin_amdgcn_global_load_lds((const __attribute__((address_space(1))) void*)g,
                                     (__attribute__((address_space(3))) void*)l, 16, 0, 0);
}

// ---------------- K0a: dtype sniff ----------------
__global__ void sniff_kernel(const unsigned short* __restrict__ xu, int* __restrict__ flag) {
    int l = threadIdx.x;  // 64 threads
    int cnt = 0;
#pragma unroll
    for (int k = 0; k < 8; ++k) {
        unsigned short u = xu[2 * (l * 8 + k)];
        int e = (u >> 7) & 0xFF;
        cnt += (e >= 96 && e <= 144) ? 1 : 0;
    }
    for (int off = 32; off > 0; off >>= 1) cnt += __shfl_down(cnt, off);
    if (l == 0) *flag = (cnt > 400) ? 1 : 0;
}

// ---------------- K0b: convert all inputs to fp32 in ws ----------------
struct ConvArgs {
    const void* p[8];
    float* o[8];
    int n[8];
};
__global__ void convert_kernel(ConvArgs A, const int* __restrict__ flag) {
    int seg = blockIdx.y;
    int n = A.n[seg];
    int isbf = *flag;
    const void* p = A.p[seg];
    float* o = A.o[seg];
    for (int i = blockIdx.x * blockDim.x + threadIdx.x; i < n; i += gridDim.x * blockDim.x) {
        float v = isbf ? b2f(((const bf16*)p)[i]) : ((const float*)p)[i];
        o[i] = v;
    }
}

// ---------------- K0c: w_ihT[c][o] = w_ih[o][c]  (coalesced write) ----------------
__global__ void transpose_wih(const float* __restrict__ wih, float* __restrict__ wihT) {
    int id = blockIdx.x * 256 + threadIdx.x;   // 98304 total
    int c = id / 384;
    int o = id - c * 384;
    wihT[id] = wih[o * 256 + c];               // read stride 1KB (L2), write coalesced
}

// ---------------- K1: q = X@Wq^T, kT = (X@Wk^T)^T ----------------
__global__ void qk_kernel(const float* __restrict__ X, const float* __restrict__ Wq,
                          const float* __restrict__ Wk,
                          float* __restrict__ q, float* __restrict__ kT) {
    int i = blockIdx.x & (N - 1);
    bool is_k = blockIdx.x >= N;
    int d = threadIdx.x;  // 0..127
    const float* W = is_k ? Wk : Wq;
    float acc = 0.f;
#pragma unroll 8
    for (int c = 0; c < D; ++c)
        acc += X[i * D + c] * W[d * D + c];
    if (is_k) kT[d * N + i] = acc;
    else      q[i * D + d] = acc;
}

// ---------------- K2: fused scores+softmax+att+gi per row i ----------------
// Phase A: s_j = v.tanh(q_i + k_j) for j>=i -> LDS wrow; block-reduce max.
// Phase B: p = exp(s-m) -> wrow; block-reduce sum; inv = rcp(sum).
// Phase C: att_d = inv * sum_j p_j * X[j,d]  (2-way j-split, combine in LDS).
// Phase D: gi[i,o] = b_ih[o] + sum_c cat(x_i,att)[c] * w_ihT[c][o] (coalesced o).
__global__ void __launch_bounds__(256) attn_kernel(const float* __restrict__ q,
                                                   const float* __restrict__ kT,
                                                   const float* __restrict__ v,
                                                   const float* __restrict__ X,
                                                   const float* __restrict__ wihT,
                                                   const float* __restrict__ b_ih,
                                                   float* __restrict__ gi) {
    int i = blockIdx.x;
    __shared__ float qs[D], vs[D], xr[D], al[D];
    __shared__ float wrow[N];
    __shared__ float red[256];
    int t = threadIdx.x;
    if (t < D) { qs[t] = q[i * D + t]; vs[t] = v[t]; xr[t] = X[i * D + t]; }
    __syncthreads();

    float sj[4];
    int cnt = 0;
    float m = -1e30f;
    for (int j = i + t; j < N; j += 256) {
        float s = 0.f;
#pragma unroll 8
        for (int d = 0; d < D; ++d) s += vs[d] * fast_tanh(qs[d] + kT[d * N + j]);
        sj[cnt++] = s;
        m = fmaxf(m, s);
    }
    red[t] = m;
    __syncthreads();
    for (int st = 128; st > 0; st >>= 1) {
        if (t < st) red[t] = fmaxf(red[t], red[t + st]);
        __syncthreads();
    }
    m = red[0];
    __syncthreads();
    float lsum = 0.f;
    {
        int it = 0;
        for (int j = i + t; j < N; j += 256, ++it) {
            float p = __expf(sj[it] - m);
            wrow[j] = p;
            lsum += p;
        }
    }
    red[t] = lsum;
    __syncthreads();
    for (int st = 128; st > 0; st >>= 1) {
        if (t < st) red[t] += red[t + st];
        __syncthreads();
    }
    float inv = fastrcp(red[0]);
    __syncthreads();   // protect red[0] before reuse below

    // Phase C
    int d = t & 127, half = t >> 7;
    float acc = 0.f;
    for (int j = i + half; j < N; j += 2) acc += wrow[j] * X[j * D + d];
    if (half) red[d] = acc;
    __syncthreads();
    if (!half) al[d] = (acc + red[d]) * inv;
    __syncthreads();

    // Phase D
    for (int o = t; o < 3 * D; o += 256) {
        float a2 = b_ih[o];
        const float* wt = wihT + o;
#pragma unroll 8
        for (int c = 0; c < D; ++c) a2 += xr[c] * wt[c * 384];
#pragma unroll 8
        for (int c = 0; c < D; ++c) a2 += al[c] * wt[(D + c) * 384];
        gi[i * 3 * D + o] = a2;
    }
}

// ---------------- K3: sequential GRU via MFMA, 4 waves, VALU-minimal ----------------
// Wave w: m-tiles mq={2w,2w+1} x tau={0,1,2}; 24 MFMA/step; weights resident as
// A-frags; biases resident as C-init frags (no per-step acc init / bias adds).
// Lane L gates row drow = 32w+16*((L>>3)&1)+4*(L>>4)+(L&3) via cndmask select.
// All LDS addressing via running byte pointers (+256 / +1536 per step).
__global__ void __launch_bounds__(256, 1) gru_kernel(const float* __restrict__ gi,
                                                     const float* __restrict__ w_hh,
                                                     const float* __restrict__ b_hh,
                                                     void* __restrict__ out,
                                                     const int* __restrict__ flag) {
    __shared__ float gi_lds[2][SB][3 * D];   // 2 x 48 KB
    __shared__ short hist[SB + 1][D];        // 8448 B
    int t = threadIdx.x;
    int w = t >> 6;
    int l = t & 63;
    int q = l >> 4;
    int nn = l & 15;
    int isbf = *flag;

    // A-frags: a[tau][mqi][kc]; A[m=nn][k=32kc+8q+j]
    bfx8 a[3][2][4];
#pragma unroll
    for (int tau = 0; tau < 3; ++tau)
#pragma unroll
        for (int mqi = 0; mqi < 2; ++mqi)
#pragma unroll
            for (int kc = 0; kc < 4; ++kc) {
                int row = 128 * tau + 16 * (2 * w + mqi) + nn;
                int k0 = 32 * kc + 8 * q;
#pragma unroll
                for (int j = 0; j < 8; ++j)
                    a[tau][mqi][kc][j] = f2bf_bits(w_hh[row * D + k0 + j]);
            }
    // bias C-init frags: C row = 4q + r of tile (tau, 2w+mqi)
    fx4 bias[3][2];
#pragma unroll
    for (int tau = 0; tau < 3; ++tau)
#pragma unroll
        for (int mqi = 0; mqi < 2; ++mqi)
#pragma unroll
            for (int r = 0; r < 4; ++r)
                bias[tau][mqi][r] = b_hh[128 * tau + 16 * (2 * w + mqi) + 4 * q + r];

    int rsel = l & 3;
    int mqsel = (l >> 3) & 1;
    int drow = 32 * w + 16 * mqsel + 4 * q + rsel;
    float h = 0.f;

    int fr = 1 + (t >> 3);
    int fc = (t & 7) * 16;

    // prefetch superstep 0
    {
        const float* src = gi;
        for (int mm = 0; mm < 12; ++mm) {
            int off = (w * 12 + mm) * 256;
            async_copy16(src + off + (l << 2), (char*)&gi_lds[0][0][0] + off * 4);
        }
    }

    for (int sb = 0; sb < NSB; ++sb) {
        int cb = sb & 1;
        if (sb == 0) {
            if (t < 64) ((int*)&hist[0][0])[t] = 0;
        } else {
            u16x8 h0 = *(const u16x8*)&hist[fr][fc];
            u16x8 h1 = *(const u16x8*)&hist[fr][fc + 8];
            int orow = (sb - 1) * SB + fr - 1;
            if (isbf) {
                *(u16x8*)((unsigned short*)out + orow * D + fc) = h0;
                *(u16x8*)((unsigned short*)out + orow * D + fc + 8) = h1;
            } else {
                float* op = (float*)out + orow * D + fc;
                fx4 f0, f1, f2, f3;
#pragma unroll
                for (int j = 0; j < 4; ++j) {
                    f0[j] = bfbits2f(h0[j]);     f1[j] = bfbits2f(h0[4 + j]);
                    f2[j] = bfbits2f(h1[j]);     f3[j] = bfbits2f(h1[4 + j]);
                }
                *(fx4*)op = f0; *(fx4*)(op + 4) = f1;
                *(fx4*)(op + 8) = f2; *(fx4*)(op + 12) = f3;
            }
            if (t < 64) ((int*)&hist[0][0])[t] = ((const int*)&hist[SB][0])[t];
        }
        asm volatile("s_waitcnt vmcnt(0) lgkmcnt(0)\ns_barrier" ::: "memory");

        if (sb + 1 < NSB) {
            const float* src = gi + (size_t)(sb + 1) * SB * 3 * D;
            for (int mm = 0; mm < 12; ++mm) {
                int off = (w * 12 + mm) * 256;
                async_copy16(src + off + (l << 2), (char*)&gi_lds[cb ^ 1][0][0] + off * 4);
            }
        }

        // running pointers for the inner loop
        const char* hrd = (const char*)&hist[0][0] + 16 * q;      // +{0,64,128,192}, step +256
        const float* gp = &gi_lds[cb][0][0] + drow;               // +{0,128,256}, step +384
        short* hwr = &hist[1][0] + drow;                          // step +128 shorts

        for (int s = 0; s < SB; ++s) {
            bfx8 b0 = *(const bfx8*)(hrd);
            bfx8 b1 = *(const bfx8*)(hrd + 64);
            bfx8 b2 = *(const bfx8*)(hrd + 128);
            bfx8 b3 = *(const bfx8*)(hrd + 192);
            float gr = gp[0];
            float gz = gp[D];
            float gn = gp[2 * D];

            fx4 acc[3][2];
#pragma unroll
            for (int tau = 0; tau < 3; ++tau)
#pragma unroll
                for (int mqi = 0; mqi < 2; ++mqi) {
                    fx4 c = bias[tau][mqi];
                    c = __builtin_amdgcn_mfma_f32_16x16x32_bf16(a[tau][mqi][0], b0, c, 0, 0, 0);
                    c = __builtin_amdgcn_mfma_f32_16x16x32_bf16(a[tau][mqi][1], b1, c, 0, 0, 0);
                    c = __builtin_amdgcn_mfma_f32_16x16x32_bf16(a[tau][mqi][2], b2, c, 0, 0, 0);
                    c = __builtin_amdgcn_mfma_f32_16x16x32_bf16(a[tau][mqi][3], b3, c, 0, 0, 0);
                    acc[tau][mqi] = c;
                }

            float ar = sel4(mqsel ? acc[0][1] : acc[0][0], rsel);
            float az = sel4(mqsel ? acc[1][1] : acc[1][0], rsel);
            float an = sel4(mqsel ? acc[2][1] : acc[2][0], rsel);
            float rr = fast_sigmoid(gr + ar);
            float zz = fast_sigmoid(gz + az);
            float nst = fast_tanh(gn + rr * an);
            h = (1.f - zz) * nst + zz * h;
            *hwr = f2bf_bits(h);     // 2 replica lanes, same addr+data: free

            hrd += 256;
            gp += 3 * D;
            hwr += D;
            asm volatile("s_waitcnt lgkmcnt(0)\ns_barrier" ::: "memory");
        }
    }
    // final flush
    {
        u16x8 h0 = *(const u16x8*)&hist[fr][fc];
        u16x8 h1 = *(const u16x8*)&hist[fr][fc + 8];
        int orow = (NSB - 1) * SB + fr - 1;
        if (isbf) {
            *(u16x8*)((unsigned short*)out + orow * D + fc) = h0;
            *(u16x8*)((unsigned short*)out + orow * D + fc + 8) = h1;
        } else {
            float* op = (float*)out + orow * D + fc;
            fx4 f0, f1, f2, f3;
#pragma unroll
            for (int j = 0; j < 4; ++j) {
                f0[j] = bfbits2f(h0[j]);     f1[j] = bfbits2f(h0[4 + j]);
                f2[j] = bfbits2f(h1[j]);     f3[j] = bfbits2f(h1[4 + j]);
            }
            *(fx4*)op = f0; *(fx4*)(op + 4) = f1;
            *(fx4*)(op + 8) = f2; *(fx4*)(op + 12) = f3;
        }
    }
}

extern "C" void kernel_launch(void* const* d_in, const int* in_sizes, int n_in,
                              void* d_out, int out_size, void* d_ws, size_t ws_size,
                              hipStream_t stream) {
    (void)in_sizes; (void)n_in; (void)out_size; (void)ws_size;

    float* w0 = (float*)d_ws;
    int*   flag = (int*)w0;
    float* Xf   = w0 + 16;
    float* Wqf  = Xf   + N * D;
    float* Wkf  = Wqf  + D * D;
    float* vf   = Wkf  + D * D;
    float* wihf = vf   + D;
    float* whhf = wihf + 3 * D * 2 * D;
    float* bihf = whhf + 3 * D * D;
    float* bhhf = bihf + 3 * D;
    float* q    = bhhf + 3 * D;
    float* kT   = q    + N * D;
    float* wihT = kT   + N * D;             // 3D x 2D transposed
    float* gi   = wihT + 3 * D * 2 * D;     // N x 3D

    sniff_kernel<<<1, 64, 0, stream>>>((const unsigned short*)d_in[0], flag);

    ConvArgs A;
    A.p[0] = d_in[0]; A.o[0] = Xf;   A.n[0] = N * D;
    A.p[1] = d_in[1]; A.o[1] = Wqf;  A.n[1] = D * D;
    A.p[2] = d_in[2]; A.o[2] = Wkf;  A.n[2] = D * D;
    A.p[3] = d_in[3]; A.o[3] = vf;   A.n[3] = D;
    A.p[4] = d_in[4]; A.o[4] = wihf; A.n[4] = 3 * D * 2 * D;
    A.p[5] = d_in[5]; A.o[5] = whhf; A.n[5] = 3 * D * D;
    A.p[6] = d_in[6]; A.o[6] = bihf; A.n[6] = 3 * D;
    A.p[7] = d_in[7]; A.o[7] = bhhf; A.n[7] = 3 * D;
    dim3 cgrid(128, 8, 1);
    convert_kernel<<<cgrid, 256, 0, stream>>>(A, flag);

    transpose_wih<<<(3 * D * 2 * D) / 256, 256, 0, stream>>>(wihf, wihT);
    qk_kernel<<<2 * N, D, 0, stream>>>(Xf, Wqf, Wkf, q, kT);
    attn_kernel<<<N, 256, 0, stream>>>(q, kT, vf, Xf, wihT, bihf, gi);
    gru_kernel<<<1, 256, 0, stream>>>(gi, whhf, bhhf, d_out, flag);
}